// Round 1
// baseline (147.686 us; speedup 1.0000x reference)
//
#include <hip/hip_runtime.h>

// SVD_Solver: weighted Kabsch per (batch, joint).  B=4096, M=64, J=24.
// Round 6: batch-block LDS staging. Old accum's global pattern was 8x 32-96B
// clusters per wave-load (25-33% line use, L1-thrash dedupe) -> ~2.5 TB/s
// effective. New accum: one block per batch, stage the batch's contiguous
// 24.75 KB (weight 6K + offset 18K + points 768B) with dense float4 loads
// (100% line utilization, ~25 KB in flight per block), compute from LDS.
// m = i*8 + kk mapping makes every LDS read <=2-way bank aliased (free)
// with ZERO padding, so LDS is a verbatim copy of global.
// solve: unchanged 1-thread-per-solve Horn 4x4 + fast-intrinsic Jacobi.

constexpr int M = 64;
constexpr int J = 24;
constexpr int NACC = 22;          // W, Wo[3], Wp[3], To[3], Tp[3], Sraw[9]
constexpr int NWS  = 15;          // S[9], Pbar[3], Qbar[3]

// LDS image (float4 units): w [0,384) | o [384,1536) | p [1536,1584)
constexpr int L4_W = 0;
constexpr int L4_O = 384;
constexpr int L4_P = 1536;
constexpr int L4_N = 1584;        // 25344 B -> 6 blocks/CU by LDS

// ---- accum: grid = B blocks x 256 threads ----
__global__ __launch_bounds__(256, 4) void accum_kernel(
    const float* __restrict__ points,   // (B, 64, 3)
    const float* __restrict__ weight,   // (B, 64, 24)
    const float* __restrict__ offset,   // (B, 64, 24, 3)
    float* __restrict__ ws,             // NWS arrays of bj_total floats (SoA)
    int bj_total)
{
    const int b = blockIdx.x;
    const int t = threadIdx.x;

    __shared__ float4 lds4[L4_N];

    const float4* wb4 = (const float4*)(weight + (size_t)b * (M * J));      // 384
    const float4* ob4 = (const float4*)(offset + (size_t)b * (M * J * 3));  // 1152
    const float4* pb4 = (const float4*)(points + (size_t)b * (M * 3));      // 48

    // Issue ALL global loads first (perfectly coalesced, ~25 KB in flight).
    float4 o0_ = ob4[t];
    float4 o1_ = ob4[t + 256];
    float4 o2_ = ob4[t + 512];
    float4 o3_ = ob4[t + 768];
    float4 w0_ = wb4[t];
    float4 o4_ = {0.f, 0.f, 0.f, 0.f};
    float4 w1_ = {0.f, 0.f, 0.f, 0.f};
    float4 p0_ = {0.f, 0.f, 0.f, 0.f};
    if (t < 128) { o4_ = ob4[1024 + t]; w1_ = wb4[256 + t]; }
    if (t < 48)  { p0_ = pb4[t]; }

    // Linear LDS copy (16-B aligned ds_write_b128 everywhere).
    lds4[L4_O + t]        = o0_;
    lds4[L4_O + 256 + t]  = o1_;
    lds4[L4_O + 512 + t]  = o2_;
    lds4[L4_O + 768 + t]  = o3_;
    lds4[L4_W + t]        = w0_;
    if (t < 128) { lds4[L4_O + 1024 + t] = o4_; lds4[L4_W + 256 + t] = w1_; }
    if (t < 48)  { lds4[L4_P + t] = p0_; }

    __syncthreads();

    const int lane = t & 63;
    const int wv   = t >> 6;
    const int kk   = lane & 7;              // m-split, lane bits 0..2 (shfl_xor 1/2/4)
    const int jj   = (lane >> 3) + wv * 8;  // joint 0..31; wave 3 -> 24..31 idle
    if (jj >= J) return;                    // whole wave 3 exits (after barrier: legal)

    const float* w_s = (const float*)lds4;            // [64][24]
    const float* o_s = (const float*)lds4 + 4 * L4_O; // [64][72]
    const float* p_s = (const float*)lds4 + 4 * L4_P; // [64][3]

    float acc[NACC];
#pragma unroll
    for (int n = 0; n < NACC; ++n) acc[n] = 0.0f;

    // m = i*8 + kk: with this mapping every LDS read below is <=2-way bank
    // aliased across the wave (2-way is free on CDNA4) without padding.
#pragma unroll
    for (int i = 0; i < M / 8; ++i) {
        const int m = i * 8 + kk;
        float w  = w_s[m * J + jj];
        float o0 = o_s[m * 72 + jj * 3 + 0];
        float o1 = o_s[m * 72 + jj * 3 + 1];
        float o2 = o_s[m * 72 + jj * 3 + 2];
        float p0 = p_s[m * 3 + 0];
        float p1 = p_s[m * 3 + 1];
        float p2 = p_s[m * 3 + 2];
        acc[0] += w;
        acc[1] = fmaf(w, o0, acc[1]);  acc[2] = fmaf(w, o1, acc[2]);  acc[3] = fmaf(w, o2, acc[3]);
        acc[4] = fmaf(w, p0, acc[4]);  acc[5] = fmaf(w, p1, acc[5]);  acc[6] = fmaf(w, p2, acc[6]);
        acc[7] += o0; acc[8] += o1; acc[9] += o2;
        acc[10] += p0; acc[11] += p1; acc[12] += p2;
        acc[13] = fmaf(o0, p0, acc[13]); acc[14] = fmaf(o0, p1, acc[14]); acc[15] = fmaf(o0, p2, acc[15]);
        acc[16] = fmaf(o1, p0, acc[16]); acc[17] = fmaf(o1, p1, acc[17]); acc[18] = fmaf(o1, p2, acc[18]);
        acc[19] = fmaf(o2, p0, acc[19]); acc[20] = fmaf(o2, p1, acc[20]); acc[21] = fmaf(o2, p2, acc[21]);
    }

    // reduce over kk (lane bits 0..2) entirely in-register
#pragma unroll
    for (int n = 0; n < NACC; ++n) {
        float v = acc[n];
        v += __shfl_xor(v, 1);
        v += __shfl_xor(v, 2);
        v += __shfl_xor(v, 4);
        acc[n] = v;
    }

    if (kk != 0) return;                    // 8 lanes/wave write

    const float inv = __builtin_amdgcn_rcpf(acc[0]);
    const float cP0 = acc[1] * inv, cP1 = acc[2] * inv, cP2 = acc[3] * inv;
    const float cQ0 = acc[4] * inv, cQ1 = acc[5] * inv, cQ2 = acc[6] * inv;
    const float To0 = acc[7], To1 = acc[8], To2 = acc[9];
    const float Tp0 = acc[10], Tp1 = acc[11], Tp2 = acc[12];
    const float fM = (float)M;
    float Sv[NWS];
    Sv[0] = acc[13] - cP0 * Tp0 - cQ0 * To0 + fM * cP0 * cQ0;
    Sv[1] = acc[14] - cP0 * Tp1 - cQ1 * To0 + fM * cP0 * cQ1;
    Sv[2] = acc[15] - cP0 * Tp2 - cQ2 * To0 + fM * cP0 * cQ2;
    Sv[3] = acc[16] - cP1 * Tp0 - cQ0 * To1 + fM * cP1 * cQ0;
    Sv[4] = acc[17] - cP1 * Tp1 - cQ1 * To1 + fM * cP1 * cQ1;
    Sv[5] = acc[18] - cP1 * Tp2 - cQ2 * To1 + fM * cP1 * cQ2;
    Sv[6] = acc[19] - cP2 * Tp0 - cQ0 * To2 + fM * cP2 * cQ0;
    Sv[7] = acc[20] - cP2 * Tp1 - cQ1 * To2 + fM * cP2 * cQ1;
    Sv[8] = acc[21] - cP2 * Tp2 - cQ2 * To2 + fM * cP2 * cQ2;
    Sv[9]  = cP0; Sv[10] = cP1; Sv[11] = cP2;
    Sv[12] = cQ0; Sv[13] = cQ1; Sv[14] = cQ2;

    const int bj = b * J + jj;              // always < bj_total
#pragma unroll
    for (int n = 0; n < NWS; ++n) ws[(size_t)n * bj_total + bj] = Sv[n];
}

// ---- fast Jacobi rotation: single-instruction rcp/rsq/sqrt ----
template<int P, int Q>
__device__ __forceinline__ void jrot(float A[4][4], float V[4][4]) {
    float apq = A[P][Q];
    float theta = (A[Q][Q] - A[P][P]) * __builtin_amdgcn_rcpf(2.0f * apq);
    float t = __builtin_amdgcn_rcpf(fabsf(theta) + __builtin_amdgcn_sqrtf(fmaf(theta, theta, 1.0f)));
    t = (theta < 0.0f) ? -t : t;
    t = (apq == 0.0f) ? 0.0f : t;            // kills inf/NaN from rcp(0)
    float c = __builtin_amdgcn_rsqf(fmaf(t, t, 1.0f));
    float s = t * c;
#pragma unroll
    for (int k = 0; k < 4; ++k) {
        float akp = A[k][P], akq = A[k][Q];
        A[k][P] = c * akp - s * akq;
        A[k][Q] = s * akp + c * akq;
    }
#pragma unroll
    for (int k = 0; k < 4; ++k) {
        float apk = A[P][k], aqk = A[Q][k];
        A[P][k] = c * apk - s * aqk;
        A[Q][k] = s * apk + c * aqk;
        float vkp = V[k][P], vkq = V[k][Q];
        V[k][P] = c * vkp - s * vkq;
        V[k][Q] = s * vkp + c * vkq;
    }
}

__device__ __forceinline__ void horn_solve(
    float S00, float S01, float S02, float S10, float S11, float S12,
    float S20, float S21, float S22,
    float cP0, float cP1, float cP2, float cQ0, float cQ1, float cQ2,
    float* __restrict__ Rout, float* __restrict__ tout)
{
    float A[4][4], V[4][4];
    A[0][0] = S00 + S11 + S22;
    A[0][1] = A[1][0] = S12 - S21;
    A[0][2] = A[2][0] = S20 - S02;
    A[0][3] = A[3][0] = S01 - S10;
    A[1][1] = S00 - S11 - S22;
    A[1][2] = A[2][1] = S01 + S10;
    A[1][3] = A[3][1] = S02 + S20;
    A[2][2] = -S00 + S11 - S22;
    A[2][3] = A[3][2] = S12 + S21;
    A[3][3] = -S00 - S11 + S22;
#pragma unroll
    for (int r = 0; r < 4; ++r)
#pragma unroll
        for (int c = 0; c < 4; ++c)
            V[r][c] = (r == c) ? 1.0f : 0.0f;

#pragma unroll 1
    for (int sweep = 0; sweep < 6; ++sweep) {
        jrot<0, 1>(A, V); jrot<0, 2>(A, V); jrot<0, 3>(A, V);
        jrot<1, 2>(A, V); jrot<1, 3>(A, V); jrot<2, 3>(A, V);
    }

    float best = A[0][0];
    float qw = V[0][0], qx = V[1][0], qy = V[2][0], qz = V[3][0];
#pragma unroll
    for (int i = 1; i < 4; ++i) {
        bool better = A[i][i] > best;
        best = better ? A[i][i] : best;
        qw = better ? V[0][i] : qw;
        qx = better ? V[1][i] : qx;
        qy = better ? V[2][i] : qy;
        qz = better ? V[3][i] : qz;
    }
    float nrm = __builtin_amdgcn_rsqf(qw * qw + qx * qx + qy * qy + qz * qz);
    qw *= nrm; qx *= nrm; qy *= nrm; qz *= nrm;

    float R00 = 1.f - 2.f * (qy * qy + qz * qz);
    float R01 = 2.f * (qx * qy - qw * qz);
    float R02 = 2.f * (qx * qz + qw * qy);
    float R10 = 2.f * (qx * qy + qw * qz);
    float R11 = 1.f - 2.f * (qx * qx + qz * qz);
    float R12 = 2.f * (qy * qz - qw * qx);
    float R20 = 2.f * (qx * qz - qw * qy);
    float R21 = 2.f * (qy * qz + qw * qx);
    float R22 = 1.f - 2.f * (qx * qx + qy * qy);

    Rout[0] = R00; Rout[1] = R01; Rout[2] = R02;
    Rout[3] = R10; Rout[4] = R11; Rout[5] = R12;
    Rout[6] = R20; Rout[7] = R21; Rout[8] = R22;
    tout[0] = cQ0 - (R00 * cP0 + R01 * cP1 + R02 * cP2);
    tout[1] = cQ1 - (R10 * cP0 + R11 * cP1 + R12 * cP2);
    tout[2] = cQ2 - (R20 * cP0 + R21 * cP1 + R22 * cP2);
}

__global__ __launch_bounds__(64) void solve_kernel(
    const float* __restrict__ ws, float* __restrict__ out, int bj_total)
{
    int tid = blockIdx.x * 64 + threadIdx.x;
    if (tid >= bj_total) return;
    float Sv[NWS];
#pragma unroll
    for (int n = 0; n < NWS; ++n) Sv[n] = ws[(size_t)n * bj_total + tid];  // coalesced SoA
    float Rr[9], tr[3];
    horn_solve(Sv[0], Sv[1], Sv[2], Sv[3], Sv[4], Sv[5], Sv[6], Sv[7], Sv[8],
               Sv[9], Sv[10], Sv[11], Sv[12], Sv[13], Sv[14], Rr, tr);
    float* Rout = out + (size_t)tid * 9;
#pragma unroll
    for (int n = 0; n < 9; ++n) Rout[n] = Rr[n];
    float* tout = out + (size_t)bj_total * 9 + (size_t)tid * 3;
    tout[0] = tr[0]; tout[1] = tr[1]; tout[2] = tr[2];
}

// ---- fallback (ws too small): fused one-thread-per-solve ----
__global__ __launch_bounds__(256) void fused_kernel(
    const float* __restrict__ points, const float* __restrict__ weight,
    const float* __restrict__ offset, float* __restrict__ out, int bj_total)
{
    int tid = blockIdx.x * blockDim.x + threadIdx.x;
    if (tid >= bj_total) return;
    int b = tid / J, j = tid - b * J;
    const float* wq = weight + (size_t)b * M * J + j;
    const float* oq = offset + ((size_t)b * M * J + j) * 3;
    const float* pq = points + (size_t)b * M * 3;
    float a[NACC];
#pragma unroll
    for (int n = 0; n < NACC; ++n) a[n] = 0.0f;
#pragma unroll 4
    for (int m = 0; m < M; ++m) {
        float w = wq[m * J];
        float o0 = oq[m * (J * 3) + 0], o1 = oq[m * (J * 3) + 1], o2 = oq[m * (J * 3) + 2];
        float p0 = pq[m * 3 + 0], p1 = pq[m * 3 + 1], p2 = pq[m * 3 + 2];
        a[0] += w;
        a[1] = fmaf(w, o0, a[1]); a[2] = fmaf(w, o1, a[2]); a[3] = fmaf(w, o2, a[3]);
        a[4] = fmaf(w, p0, a[4]); a[5] = fmaf(w, p1, a[5]); a[6] = fmaf(w, p2, a[6]);
        a[7] += o0; a[8] += o1; a[9] += o2;
        a[10] += p0; a[11] += p1; a[12] += p2;
        a[13] = fmaf(o0, p0, a[13]); a[14] = fmaf(o0, p1, a[14]); a[15] = fmaf(o0, p2, a[15]);
        a[16] = fmaf(o1, p0, a[16]); a[17] = fmaf(o1, p1, a[17]); a[18] = fmaf(o1, p2, a[18]);
        a[19] = fmaf(o2, p0, a[19]); a[20] = fmaf(o2, p1, a[20]); a[21] = fmaf(o2, p2, a[21]);
    }
    float inv = __builtin_amdgcn_rcpf(a[0]);
    float cP0 = a[1] * inv, cP1 = a[2] * inv, cP2 = a[3] * inv;
    float cQ0 = a[4] * inv, cQ1 = a[5] * inv, cQ2 = a[6] * inv;
    const float fM = (float)M;
    float S00 = a[13] - cP0 * a[10] - cQ0 * a[7] + fM * cP0 * cQ0;
    float S01 = a[14] - cP0 * a[11] - cQ1 * a[7] + fM * cP0 * cQ1;
    float S02 = a[15] - cP0 * a[12] - cQ2 * a[7] + fM * cP0 * cQ2;
    float S10 = a[16] - cP1 * a[10] - cQ0 * a[8] + fM * cP1 * cQ0;
    float S11 = a[17] - cP1 * a[11] - cQ1 * a[8] + fM * cP1 * cQ1;
    float S12 = a[18] - cP1 * a[12] - cQ2 * a[8] + fM * cP1 * cQ2;
    float S20 = a[19] - cP2 * a[10] - cQ0 * a[9] + fM * cP2 * cQ0;
    float S21 = a[20] - cP2 * a[11] - cQ1 * a[9] + fM * cP2 * cQ1;
    float S22 = a[21] - cP2 * a[12] - cQ2 * a[9] + fM * cP2 * cQ2;
    float Rr[9], tr[3];
    horn_solve(S00, S01, S02, S10, S11, S12, S20, S21, S22,
               cP0, cP1, cP2, cQ0, cQ1, cQ2, Rr, tr);
    float* Rout = out + (size_t)tid * 9;
#pragma unroll
    for (int n = 0; n < 9; ++n) Rout[n] = Rr[n];
    float* tout = out + (size_t)bj_total * 9 + (size_t)tid * 3;
    tout[0] = tr[0]; tout[1] = tr[1]; tout[2] = tr[2];
}

extern "C" void kernel_launch(void* const* d_in, const int* in_sizes, int n_in,
                              void* d_out, int out_size, void* d_ws, size_t ws_size,
                              hipStream_t stream) {
    const float* points = (const float*)d_in[0];
    const float* weight = (const float*)d_in[1];
    const float* offset = (const float*)d_in[2];
    float* out = (float*)d_out;

    int B = in_sizes[0] / (M * 3);
    int bj_total = B * J;

    size_t need = (size_t)NWS * bj_total * sizeof(float);   // 5.9 MB at B=4096
    if (ws_size >= need) {
        accum_kernel<<<B, 256, 0, stream>>>(points, weight, offset, (float*)d_ws, bj_total);
        solve_kernel<<<(bj_total + 63) / 64, 64, 0, stream>>>((const float*)d_ws, out, bj_total);
    } else {
        fused_kernel<<<(bj_total + 255) / 256, 256, 0, stream>>>(points, weight, offset, out, bj_total);
    }
}

// Round 2
// 144.087 us; speedup vs baseline: 1.0250x; 1.0250x over previous
//
#include <hip/hip_runtime.h>

// SVD_Solver: weighted Kabsch per (batch, joint).  B=4096, M=64, J=24.
// Round 7: SINGLE fused kernel, zero workspace. R1 showed dur_us is dominated
// by harness poison fills (~45 us x several, in the timed window); our kernels
// are ~15-25 us of the 147. Remaining controllable cost: 2nd launch + ws
// round-trip (11.8 MB) + solve kernel. Fix: fuse Horn solve into the accum
// block via an LDS Sv handoff -- ONE wave per block runs the 24 solves after
// a barrier (not the divergent 24/256-lane in-path Jacobi that regressed in
// R4), and its ~3000 cyc of VALU hides completely under the HBM stream of
// neighboring blocks (accum is memory-bound, VALU idle).
// Staging: batch-contiguous 24.75 KB via dense float4 loads (100% line use).
// m = i*8 + kk mapping keeps every LDS read <=2-way bank aliased (free),
// LDS image is a verbatim copy of global.

constexpr int M = 64;
constexpr int J = 24;
constexpr int NACC = 22;          // W, Wo[3], Wp[3], To[3], Tp[3], Sraw[9]
constexpr int NWS  = 15;          // S[9], Pbar[3], Qbar[3]

// LDS image (float4 units): w [0,384) | o [384,1536) | p [1536,1584)
constexpr int L4_W = 0;
constexpr int L4_O = 384;
constexpr int L4_P = 1536;
constexpr int L4_N = 1584;        // 25344 B -> 6 blocks/CU by LDS

// ---- fast Jacobi rotation: single-instruction rcp/rsq/sqrt ----
template<int P, int Q>
__device__ __forceinline__ void jrot(float A[4][4], float V[4][4]) {
    float apq = A[P][Q];
    float theta = (A[Q][Q] - A[P][P]) * __builtin_amdgcn_rcpf(2.0f * apq);
    float t = __builtin_amdgcn_rcpf(fabsf(theta) + __builtin_amdgcn_sqrtf(fmaf(theta, theta, 1.0f)));
    t = (theta < 0.0f) ? -t : t;
    t = (apq == 0.0f) ? 0.0f : t;            // kills inf/NaN from rcp(0)
    float c = __builtin_amdgcn_rsqf(fmaf(t, t, 1.0f));
    float s = t * c;
#pragma unroll
    for (int k = 0; k < 4; ++k) {
        float akp = A[k][P], akq = A[k][Q];
        A[k][P] = c * akp - s * akq;
        A[k][Q] = s * akp + c * akq;
    }
#pragma unroll
    for (int k = 0; k < 4; ++k) {
        float apk = A[P][k], aqk = A[Q][k];
        A[P][k] = c * apk - s * aqk;
        A[Q][k] = s * apk + c * aqk;
        float vkp = V[k][P], vkq = V[k][Q];
        V[k][P] = c * vkp - s * vkq;
        V[k][Q] = s * vkp + c * vkq;
    }
}

__device__ __forceinline__ void horn_solve(
    float S00, float S01, float S02, float S10, float S11, float S12,
    float S20, float S21, float S22,
    float cP0, float cP1, float cP2, float cQ0, float cQ1, float cQ2,
    float* __restrict__ Rout, float* __restrict__ tout)
{
    float A[4][4], V[4][4];
    A[0][0] = S00 + S11 + S22;
    A[0][1] = A[1][0] = S12 - S21;
    A[0][2] = A[2][0] = S20 - S02;
    A[0][3] = A[3][0] = S01 - S10;
    A[1][1] = S00 - S11 - S22;
    A[1][2] = A[2][1] = S01 + S10;
    A[1][3] = A[3][1] = S02 + S20;
    A[2][2] = -S00 + S11 - S22;
    A[2][3] = A[3][2] = S12 + S21;
    A[3][3] = -S00 - S11 + S22;
#pragma unroll
    for (int r = 0; r < 4; ++r)
#pragma unroll
        for (int c = 0; c < 4; ++c)
            V[r][c] = (r == c) ? 1.0f : 0.0f;

#pragma unroll 1
    for (int sweep = 0; sweep < 6; ++sweep) {
        jrot<0, 1>(A, V); jrot<0, 2>(A, V); jrot<0, 3>(A, V);
        jrot<1, 2>(A, V); jrot<1, 3>(A, V); jrot<2, 3>(A, V);
    }

    float best = A[0][0];
    float qw = V[0][0], qx = V[1][0], qy = V[2][0], qz = V[3][0];
#pragma unroll
    for (int i = 1; i < 4; ++i) {
        bool better = A[i][i] > best;
        best = better ? A[i][i] : best;
        qw = better ? V[0][i] : qw;
        qx = better ? V[1][i] : qx;
        qy = better ? V[2][i] : qy;
        qz = better ? V[3][i] : qz;
    }
    float nrm = __builtin_amdgcn_rsqf(qw * qw + qx * qx + qy * qy + qz * qz);
    qw *= nrm; qx *= nrm; qy *= nrm; qz *= nrm;

    float R00 = 1.f - 2.f * (qy * qy + qz * qz);
    float R01 = 2.f * (qx * qy - qw * qz);
    float R02 = 2.f * (qx * qz + qw * qy);
    float R10 = 2.f * (qx * qy + qw * qz);
    float R11 = 1.f - 2.f * (qx * qx + qz * qz);
    float R12 = 2.f * (qy * qz - qw * qx);
    float R20 = 2.f * (qx * qz - qw * qy);
    float R21 = 2.f * (qy * qz + qw * qx);
    float R22 = 1.f - 2.f * (qx * qx + qy * qy);

    Rout[0] = R00; Rout[1] = R01; Rout[2] = R02;
    Rout[3] = R10; Rout[4] = R11; Rout[5] = R12;
    Rout[6] = R20; Rout[7] = R21; Rout[8] = R22;
    tout[0] = cQ0 - (R00 * cP0 + R01 * cP1 + R02 * cP2);
    tout[1] = cQ1 - (R10 * cP0 + R11 * cP1 + R12 * cP2);
    tout[2] = cQ2 - (R20 * cP0 + R21 * cP1 + R22 * cP2);
}

// ---- fused: grid = B blocks x 256 threads, zero workspace ----
__global__ __launch_bounds__(256, 4) void kabsch_fused(
    const float* __restrict__ points,   // (B, 64, 3)
    const float* __restrict__ weight,   // (B, 64, 24)
    const float* __restrict__ offset,   // (B, 64, 24, 3)
    float* __restrict__ out,            // R (bj,9) then t (bj,3)
    int bj_total)
{
    const int b = blockIdx.x;
    const int t = threadIdx.x;

    __shared__ float4 lds4[L4_N];

    const float4* wb4 = (const float4*)(weight + (size_t)b * (M * J));      // 384
    const float4* ob4 = (const float4*)(offset + (size_t)b * (M * J * 3));  // 1152
    const float4* pb4 = (const float4*)(points + (size_t)b * (M * 3));      // 48

    // Issue ALL global loads first (perfectly coalesced, ~25 KB in flight).
    float4 o0_ = ob4[t];
    float4 o1_ = ob4[t + 256];
    float4 o2_ = ob4[t + 512];
    float4 o3_ = ob4[t + 768];
    float4 w0_ = wb4[t];
    float4 o4_ = {0.f, 0.f, 0.f, 0.f};
    float4 w1_ = {0.f, 0.f, 0.f, 0.f};
    float4 p0_ = {0.f, 0.f, 0.f, 0.f};
    if (t < 128) { o4_ = ob4[1024 + t]; w1_ = wb4[256 + t]; }
    if (t < 48)  { p0_ = pb4[t]; }

    // Linear LDS copy (16-B aligned ds_write_b128 everywhere).
    lds4[L4_O + t]        = o0_;
    lds4[L4_O + 256 + t]  = o1_;
    lds4[L4_O + 512 + t]  = o2_;
    lds4[L4_O + 768 + t]  = o3_;
    lds4[L4_W + t]        = w0_;
    if (t < 128) { lds4[L4_O + 1024 + t] = o4_; lds4[L4_W + 256 + t] = w1_; }
    if (t < 48)  { lds4[L4_P + t] = p0_; }

    __syncthreads();

    const int lane = t & 63;
    const int wv   = t >> 6;
    const int kk   = lane & 7;              // m-split, lane bits 0..2 (shfl_xor 1/2/4)
    const int jj   = (lane >> 3) + wv * 8;  // joint 0..31; wave 3 (24..31) skips compute
    const bool prod = (jj < J);             // wave-uniform: waves 0-2 all true, wave 3 all false

    float acc[NACC];
#pragma unroll
    for (int n = 0; n < NACC; ++n) acc[n] = 0.0f;

    if (prod) {
        const float* w_s = (const float*)lds4;            // [64][24]
        const float* o_s = (const float*)lds4 + 4 * L4_O; // [64][72]
        const float* p_s = (const float*)lds4 + 4 * L4_P; // [64][3]

        // m = i*8 + kk: every LDS read <=2-way bank aliased (free on CDNA4).
#pragma unroll
        for (int i = 0; i < M / 8; ++i) {
            const int m = i * 8 + kk;
            float w  = w_s[m * J + jj];
            float o0 = o_s[m * 72 + jj * 3 + 0];
            float o1 = o_s[m * 72 + jj * 3 + 1];
            float o2 = o_s[m * 72 + jj * 3 + 2];
            float p0 = p_s[m * 3 + 0];
            float p1 = p_s[m * 3 + 1];
            float p2 = p_s[m * 3 + 2];
            acc[0] += w;
            acc[1] = fmaf(w, o0, acc[1]);  acc[2] = fmaf(w, o1, acc[2]);  acc[3] = fmaf(w, o2, acc[3]);
            acc[4] = fmaf(w, p0, acc[4]);  acc[5] = fmaf(w, p1, acc[5]);  acc[6] = fmaf(w, p2, acc[6]);
            acc[7] += o0; acc[8] += o1; acc[9] += o2;
            acc[10] += p0; acc[11] += p1; acc[12] += p2;
            acc[13] = fmaf(o0, p0, acc[13]); acc[14] = fmaf(o0, p1, acc[14]); acc[15] = fmaf(o0, p2, acc[15]);
            acc[16] = fmaf(o1, p0, acc[16]); acc[17] = fmaf(o1, p1, acc[17]); acc[18] = fmaf(o1, p2, acc[18]);
            acc[19] = fmaf(o2, p0, acc[19]); acc[20] = fmaf(o2, p1, acc[20]); acc[21] = fmaf(o2, p2, acc[21]);
        }

        // reduce over kk (lane bits 0..2) entirely in-register
#pragma unroll
        for (int n = 0; n < NACC; ++n) {
            float v = acc[n];
            v += __shfl_xor(v, 1);
            v += __shfl_xor(v, 2);
            v += __shfl_xor(v, 4);
            acc[n] = v;
        }
    }

    __syncthreads();                        // all LDS reads done -> safe to reuse w region

    float* sv_s = (float*)lds4;             // 24*15 floats = 1440 B, overlaps old w image
    if (prod && kk == 0) {
        const float inv = __builtin_amdgcn_rcpf(acc[0]);
        const float cP0 = acc[1] * inv, cP1 = acc[2] * inv, cP2 = acc[3] * inv;
        const float cQ0 = acc[4] * inv, cQ1 = acc[5] * inv, cQ2 = acc[6] * inv;
        const float To0 = acc[7], To1 = acc[8], To2 = acc[9];
        const float Tp0 = acc[10], Tp1 = acc[11], Tp2 = acc[12];
        const float fM = (float)M;
        float Sv[NWS];
        Sv[0] = acc[13] - cP0 * Tp0 - cQ0 * To0 + fM * cP0 * cQ0;
        Sv[1] = acc[14] - cP0 * Tp1 - cQ1 * To0 + fM * cP0 * cQ1;
        Sv[2] = acc[15] - cP0 * Tp2 - cQ2 * To0 + fM * cP0 * cQ2;
        Sv[3] = acc[16] - cP1 * Tp0 - cQ0 * To1 + fM * cP1 * cQ0;
        Sv[4] = acc[17] - cP1 * Tp1 - cQ1 * To1 + fM * cP1 * cQ1;
        Sv[5] = acc[18] - cP1 * Tp2 - cQ2 * To1 + fM * cP1 * cQ2;
        Sv[6] = acc[19] - cP2 * Tp0 - cQ0 * To2 + fM * cP2 * cQ0;
        Sv[7] = acc[20] - cP2 * Tp1 - cQ1 * To2 + fM * cP2 * cQ1;
        Sv[8] = acc[21] - cP2 * Tp2 - cQ2 * To2 + fM * cP2 * cQ2;
        Sv[9]  = cP0; Sv[10] = cP1; Sv[11] = cP2;
        Sv[12] = cQ0; Sv[13] = cQ1; Sv[14] = cQ2;
#pragma unroll
        for (int n = 0; n < NWS; ++n) sv_s[n * J + jj] = Sv[n];  // 8 consecutive addrs/wave
    }

    __syncthreads();

    // One wave (threads 0..23 of wave 0) runs the 24 solves; waves 1-3 retire.
    if (t < J) {
        float v[NWS];
#pragma unroll
        for (int n = 0; n < NWS; ++n) v[n] = sv_s[n * J + t];    // consecutive, conflict-free
        float Rr[9], tr[3];
        horn_solve(v[0], v[1], v[2], v[3], v[4], v[5], v[6], v[7], v[8],
                   v[9], v[10], v[11], v[12], v[13], v[14], Rr, tr);
        const int bj = b * J + t;
        float* Rout = out + (size_t)bj * 9;
#pragma unroll
        for (int n = 0; n < 9; ++n) Rout[n] = Rr[n];             // 864 B contiguous per block
        float* tout = out + (size_t)bj_total * 9 + (size_t)bj * 3;
        tout[0] = tr[0]; tout[1] = tr[1]; tout[2] = tr[2];
    }
}

extern "C" void kernel_launch(void* const* d_in, const int* in_sizes, int n_in,
                              void* d_out, int out_size, void* d_ws, size_t ws_size,
                              hipStream_t stream) {
    const float* points = (const float*)d_in[0];
    const float* weight = (const float*)d_in[1];
    const float* offset = (const float*)d_in[2];
    float* out = (float*)d_out;

    int B = in_sizes[0] / (M * 3);
    int bj_total = B * J;

    kabsch_fused<<<B, 256, 0, stream>>>(points, weight, offset, out, bj_total);
}

// Round 3
// 142.505 us; speedup vs baseline: 1.0364x; 1.0111x over previous
//
#include <hip/hip_runtime.h>

// SVD_Solver: weighted Kabsch per (batch, joint).  B=4096, M=64, J=24.
// Round 8: amortize per-block overhead. R2 evidence: dur identical at 50.7 MB
// vs 4.7 MB HBM fetch (L3-warm) -> NOT BW-bound; 3 different accum structures
// all ~44-52 us -> per-workgroup fixed cost (~12.7 ns x 4096 blocks) dominates.
// Fix: BPG=4 batches per block (grid 1024), software-pipelined:
//   loop g: ds_write staged regs / barrier / issue g+1 global loads (latency
//   hides under accum) / accum + shfl-reduce / Sv -> LDS / barrier
// then ONE solve phase: threads 0..95 run 96 Horn solves (tail amortized 4x).
// LDS 31.3 KB -> 5 blocks/CU cap; 1024 blocks = 4/CU -> whole grid resident.

constexpr int M = 64;
constexpr int J = 24;
constexpr int NACC = 22;          // W, Wo[3], Wp[3], To[3], Tp[3], Sraw[9]
constexpr int NWS  = 15;          // S[9], Pbar[3], Qbar[3]
constexpr int BPG  = 4;           // batches per block

// LDS image (float4 units): w [0,384) | o [384,1536) | p [1536,1584)
constexpr int L4_W = 0;
constexpr int L4_O = 384;
constexpr int L4_P = 1536;
constexpr int L4_N = 1584;        // 25344 B

// ---- fast Jacobi rotation: single-instruction rcp/rsq/sqrt ----
template<int P, int Q>
__device__ __forceinline__ void jrot(float A[4][4], float V[4][4]) {
    float apq = A[P][Q];
    float theta = (A[Q][Q] - A[P][P]) * __builtin_amdgcn_rcpf(2.0f * apq);
    float t = __builtin_amdgcn_rcpf(fabsf(theta) + __builtin_amdgcn_sqrtf(fmaf(theta, theta, 1.0f)));
    t = (theta < 0.0f) ? -t : t;
    t = (apq == 0.0f) ? 0.0f : t;            // kills inf/NaN from rcp(0)
    float c = __builtin_amdgcn_rsqf(fmaf(t, t, 1.0f));
    float s = t * c;
#pragma unroll
    for (int k = 0; k < 4; ++k) {
        float akp = A[k][P], akq = A[k][Q];
        A[k][P] = c * akp - s * akq;
        A[k][Q] = s * akp + c * akq;
    }
#pragma unroll
    for (int k = 0; k < 4; ++k) {
        float apk = A[P][k], aqk = A[Q][k];
        A[P][k] = c * apk - s * aqk;
        A[Q][k] = s * apk + c * aqk;
        float vkp = V[k][P], vkq = V[k][Q];
        V[k][P] = c * vkp - s * vkq;
        V[k][Q] = s * vkp + c * vkq;
    }
}

__device__ __forceinline__ void horn_solve(
    float S00, float S01, float S02, float S10, float S11, float S12,
    float S20, float S21, float S22,
    float cP0, float cP1, float cP2, float cQ0, float cQ1, float cQ2,
    float* __restrict__ Rout, float* __restrict__ tout)
{
    float A[4][4], V[4][4];
    A[0][0] = S00 + S11 + S22;
    A[0][1] = A[1][0] = S12 - S21;
    A[0][2] = A[2][0] = S20 - S02;
    A[0][3] = A[3][0] = S01 - S10;
    A[1][1] = S00 - S11 - S22;
    A[1][2] = A[2][1] = S01 + S10;
    A[1][3] = A[3][1] = S02 + S20;
    A[2][2] = -S00 + S11 - S22;
    A[2][3] = A[3][2] = S12 + S21;
    A[3][3] = -S00 - S11 + S22;
#pragma unroll
    for (int r = 0; r < 4; ++r)
#pragma unroll
        for (int c = 0; c < 4; ++c)
            V[r][c] = (r == c) ? 1.0f : 0.0f;

#pragma unroll 1
    for (int sweep = 0; sweep < 6; ++sweep) {
        jrot<0, 1>(A, V); jrot<0, 2>(A, V); jrot<0, 3>(A, V);
        jrot<1, 2>(A, V); jrot<1, 3>(A, V); jrot<2, 3>(A, V);
    }

    float best = A[0][0];
    float qw = V[0][0], qx = V[1][0], qy = V[2][0], qz = V[3][0];
#pragma unroll
    for (int i = 1; i < 4; ++i) {
        bool better = A[i][i] > best;
        best = better ? A[i][i] : best;
        qw = better ? V[0][i] : qw;
        qx = better ? V[1][i] : qx;
        qy = better ? V[2][i] : qy;
        qz = better ? V[3][i] : qz;
    }
    float nrm = __builtin_amdgcn_rsqf(qw * qw + qx * qx + qy * qy + qz * qz);
    qw *= nrm; qx *= nrm; qy *= nrm; qz *= nrm;

    float R00 = 1.f - 2.f * (qy * qy + qz * qz);
    float R01 = 2.f * (qx * qy - qw * qz);
    float R02 = 2.f * (qx * qz + qw * qy);
    float R10 = 2.f * (qx * qy + qw * qz);
    float R11 = 1.f - 2.f * (qx * qx + qz * qz);
    float R12 = 2.f * (qy * qz - qw * qx);
    float R20 = 2.f * (qx * qz - qw * qy);
    float R21 = 2.f * (qy * qz + qw * qx);
    float R22 = 1.f - 2.f * (qx * qx + qy * qy);

    Rout[0] = R00; Rout[1] = R01; Rout[2] = R02;
    Rout[3] = R10; Rout[4] = R11; Rout[5] = R12;
    Rout[6] = R20; Rout[7] = R21; Rout[8] = R22;
    tout[0] = cQ0 - (R00 * cP0 + R01 * cP1 + R02 * cP2);
    tout[1] = cQ1 - (R10 * cP0 + R11 * cP1 + R12 * cP2);
    tout[2] = cQ2 - (R20 * cP0 + R21 * cP1 + R22 * cP2);
}

// ---- fused, multi-batch: grid = ceil(B/BPG) x 256 threads ----
__global__ __launch_bounds__(256, 4) void kabsch_fused(
    const float* __restrict__ points,   // (B, 64, 3)
    const float* __restrict__ weight,   // (B, 64, 24)
    const float* __restrict__ offset,   // (B, 64, 24, 3)
    float* __restrict__ out,            // R (bj,9) then t (bj,3)
    int B, int bj_total)
{
    const int b0 = blockIdx.x * BPG;
    const int t  = threadIdx.x;

    __shared__ float4 lds4[L4_N];
    __shared__ float  sv_s[BPG][NWS][J + 1];   // +1 pad, 6000 B

    const int lane = t & 63;
    const int wv   = t >> 6;
    const int kk   = lane & 7;              // m-split, lane bits 0..2
    const int jj   = (lane >> 3) + wv * 8;  // joint 0..31; wave 3 skips accum
    const bool prod = (jj < J);

    // ---- register prefetch lambda: batch bb -> regs (clamped, safe) ----
    float4 r_o0, r_o1, r_o2, r_o3, r_o4, r_w0, r_w1, r_p0;
    auto load_batch = [&](int bb) {
        bb = bb < B ? bb : B - 1;
        const float4* wb4 = (const float4*)(weight + (size_t)bb * (M * J));
        const float4* ob4 = (const float4*)(offset + (size_t)bb * (M * J * 3));
        const float4* pb4 = (const float4*)(points + (size_t)bb * (M * 3));
        r_o0 = ob4[t];
        r_o1 = ob4[t + 256];
        r_o2 = ob4[t + 512];
        r_o3 = ob4[t + 768];
        r_w0 = wb4[t];
        if (t < 128) { r_o4 = ob4[1024 + t]; r_w1 = wb4[256 + t]; }
        if (t < 48)  { r_p0 = pb4[t]; }
    };

    load_batch(b0);                          // prologue: batch 0 in flight

#pragma unroll 1
    for (int g = 0; g < BPG; ++g) {
        // stage current regs into LDS (verbatim linear image)
        lds4[L4_O + t]       = r_o0;
        lds4[L4_O + 256 + t] = r_o1;
        lds4[L4_O + 512 + t] = r_o2;
        lds4[L4_O + 768 + t] = r_o3;
        lds4[L4_W + t]       = r_w0;
        if (t < 128) { lds4[L4_O + 1024 + t] = r_o4; lds4[L4_W + 256 + t] = r_w1; }
        if (t < 48)  { lds4[L4_P + t] = r_p0; }

        __syncthreads();

        // issue NEXT batch's global loads now -- latency hides under accum
        if (g + 1 < BPG) load_batch(b0 + g + 1);

        float acc[NACC];
#pragma unroll
        for (int n = 0; n < NACC; ++n) acc[n] = 0.0f;

        if (prod) {
            const float* w_s = (const float*)lds4;            // [64][24]
            const float* o_s = (const float*)lds4 + 4 * L4_O; // [64][72]
            const float* p_s = (const float*)lds4 + 4 * L4_P; // [64][3]

            // m = i*8 + kk: every LDS read <=2-way bank aliased (free).
#pragma unroll
            for (int i = 0; i < M / 8; ++i) {
                const int m = i * 8 + kk;
                float w  = w_s[m * J + jj];
                float o0 = o_s[m * 72 + jj * 3 + 0];
                float o1 = o_s[m * 72 + jj * 3 + 1];
                float o2 = o_s[m * 72 + jj * 3 + 2];
                float p0 = p_s[m * 3 + 0];
                float p1 = p_s[m * 3 + 1];
                float p2 = p_s[m * 3 + 2];
                acc[0] += w;
                acc[1] = fmaf(w, o0, acc[1]);  acc[2] = fmaf(w, o1, acc[2]);  acc[3] = fmaf(w, o2, acc[3]);
                acc[4] = fmaf(w, p0, acc[4]);  acc[5] = fmaf(w, p1, acc[5]);  acc[6] = fmaf(w, p2, acc[6]);
                acc[7] += o0; acc[8] += o1; acc[9] += o2;
                acc[10] += p0; acc[11] += p1; acc[12] += p2;
                acc[13] = fmaf(o0, p0, acc[13]); acc[14] = fmaf(o0, p1, acc[14]); acc[15] = fmaf(o0, p2, acc[15]);
                acc[16] = fmaf(o1, p0, acc[16]); acc[17] = fmaf(o1, p1, acc[17]); acc[18] = fmaf(o1, p2, acc[18]);
                acc[19] = fmaf(o2, p0, acc[19]); acc[20] = fmaf(o2, p1, acc[20]); acc[21] = fmaf(o2, p2, acc[21]);
            }

            // reduce over kk (lane bits 0..2) entirely in-register
#pragma unroll
            for (int n = 0; n < NACC; ++n) {
                float v = acc[n];
                v += __shfl_xor(v, 1);
                v += __shfl_xor(v, 2);
                v += __shfl_xor(v, 4);
                acc[n] = v;
            }

            if (kk == 0) {
                const float inv = __builtin_amdgcn_rcpf(acc[0]);
                const float cP0 = acc[1] * inv, cP1 = acc[2] * inv, cP2 = acc[3] * inv;
                const float cQ0 = acc[4] * inv, cQ1 = acc[5] * inv, cQ2 = acc[6] * inv;
                const float To0 = acc[7], To1 = acc[8], To2 = acc[9];
                const float Tp0 = acc[10], Tp1 = acc[11], Tp2 = acc[12];
                const float fM = (float)M;
                sv_s[g][0][jj]  = acc[13] - cP0 * Tp0 - cQ0 * To0 + fM * cP0 * cQ0;
                sv_s[g][1][jj]  = acc[14] - cP0 * Tp1 - cQ1 * To0 + fM * cP0 * cQ1;
                sv_s[g][2][jj]  = acc[15] - cP0 * Tp2 - cQ2 * To0 + fM * cP0 * cQ2;
                sv_s[g][3][jj]  = acc[16] - cP1 * Tp0 - cQ0 * To1 + fM * cP1 * cQ0;
                sv_s[g][4][jj]  = acc[17] - cP1 * Tp1 - cQ1 * To1 + fM * cP1 * cQ1;
                sv_s[g][5][jj]  = acc[18] - cP1 * Tp2 - cQ2 * To1 + fM * cP1 * cQ2;
                sv_s[g][6][jj]  = acc[19] - cP2 * Tp0 - cQ0 * To2 + fM * cP2 * cQ0;
                sv_s[g][7][jj]  = acc[20] - cP2 * Tp1 - cQ1 * To2 + fM * cP2 * cQ1;
                sv_s[g][8][jj]  = acc[21] - cP2 * Tp2 - cQ2 * To2 + fM * cP2 * cQ2;
                sv_s[g][9][jj]  = cP0; sv_s[g][10][jj] = cP1; sv_s[g][11][jj] = cP2;
                sv_s[g][12][jj] = cQ0; sv_s[g][13][jj] = cQ1; sv_s[g][14][jj] = cQ2;
            }
        }

        __syncthreads();   // accum reads done -> next iter may overwrite lds4
    }

    // ---- solve phase: threads 0..BPG*J-1, one Horn solve each ----
    if (t < BPG * J) {
        const int g  = t / J;
        const int j  = t - g * J;
        const int bb = b0 + g;
        if (bb < B) {
            float v[NWS];
#pragma unroll
            for (int n = 0; n < NWS; ++n) v[n] = sv_s[g][n][j];
            float Rr[9], tr[3];
            horn_solve(v[0], v[1], v[2], v[3], v[4], v[5], v[6], v[7], v[8],
                       v[9], v[10], v[11], v[12], v[13], v[14], Rr, tr);
            const int bj = bb * J + j;
            float* Rout = out + (size_t)bj * 9;
#pragma unroll
            for (int n = 0; n < 9; ++n) Rout[n] = Rr[n];
            float* tout = out + (size_t)bj_total * 9 + (size_t)bj * 3;
            tout[0] = tr[0]; tout[1] = tr[1]; tout[2] = tr[2];
        }
    }
}

extern "C" void kernel_launch(void* const* d_in, const int* in_sizes, int n_in,
                              void* d_out, int out_size, void* d_ws, size_t ws_size,
                              hipStream_t stream) {
    const float* points = (const float*)d_in[0];
    const float* weight = (const float*)d_in[1];
    const float* offset = (const float*)d_in[2];
    float* out = (float*)d_out;

    int B = in_sizes[0] / (M * 3);
    int bj_total = B * J;
    int grid = (B + BPG - 1) / BPG;

    kabsch_fused<<<grid, 256, 0, stream>>>(points, weight, offset, out, B, bj_total);
}

// Round 5
// 140.241 us; speedup vs baseline: 1.0531x; 1.0161x over previous
//
#include <hip/hip_runtime.h>

// SVD_Solver: weighted Kabsch per (batch, joint).  B=4096, M=64, J=24.
// Round 9b: resubmit of R9 (R4 bench was an infra failure: container died
// before any dispatch; kernel audited bounds-safe). Stall-free wave-per-batch.
// Evidence trail: R2 cold(50MB)==warm(5MB) duration -> not BW-bound; R3 grid
// 4096->1024 moved 52->49us -> not dispatch bound; VALUBusy 27% -> not VALU
// bound. Remaining suspect: barrier-coupled serialization + solve tail on the
// per-CU critical path -> minimize CYCLES, decouple waves.
// Structure: each 64-lane wave owns ONE batch end-to-end. lane=(jj,kk):
// jj=joint (0..23), kk=half (m in kk*32..kk*32+31). Direct global loads
// (no LDS staging, no staging barriers -- traffic pattern proven irrelevant),
// 32-iter unrolled accum, ONE shfl_xor pair-reduce, Sv -> 1.5KB LDS, ONE
// barrier, 48 solves on wave 0. 128-thread blocks, grid B/2: 8 blocks/CU,
// 16 waves/CU, all independent -- loads pipeline freely, waves never couple.

constexpr int M = 64;
constexpr int J = 24;
constexpr int NACC = 22;          // W, Wo[3], Wp[3], To[3], Tp[3], Sraw[9]
constexpr int NWS  = 15;          // S[9], Pbar[3], Qbar[3]
constexpr int WPB  = 2;           // waves (=batches) per block

// ---- fast Jacobi rotation: single-instruction rcp/rsq/sqrt ----
template<int P, int Q>
__device__ __forceinline__ void jrot(float A[4][4], float V[4][4]) {
    float apq = A[P][Q];
    float theta = (A[Q][Q] - A[P][P]) * __builtin_amdgcn_rcpf(2.0f * apq);
    float t = __builtin_amdgcn_rcpf(fabsf(theta) + __builtin_amdgcn_sqrtf(fmaf(theta, theta, 1.0f)));
    t = (theta < 0.0f) ? -t : t;
    t = (apq == 0.0f) ? 0.0f : t;            // kills inf/NaN from rcp(0)
    float c = __builtin_amdgcn_rsqf(fmaf(t, t, 1.0f));
    float s = t * c;
#pragma unroll
    for (int k = 0; k < 4; ++k) {
        float akp = A[k][P], akq = A[k][Q];
        A[k][P] = c * akp - s * akq;
        A[k][Q] = s * akp + c * akq;
    }
#pragma unroll
    for (int k = 0; k < 4; ++k) {
        float apk = A[P][k], aqk = A[Q][k];
        A[P][k] = c * apk - s * aqk;
        A[Q][k] = s * apk + c * aqk;
        float vkp = V[k][P], vkq = V[k][Q];
        V[k][P] = c * vkp - s * vkq;
        V[k][Q] = s * vkp + c * vkq;
    }
}

__device__ __forceinline__ void horn_solve(
    float S00, float S01, float S02, float S10, float S11, float S12,
    float S20, float S21, float S22,
    float cP0, float cP1, float cP2, float cQ0, float cQ1, float cQ2,
    float* __restrict__ Rout, float* __restrict__ tout)
{
    float A[4][4], V[4][4];
    A[0][0] = S00 + S11 + S22;
    A[0][1] = A[1][0] = S12 - S21;
    A[0][2] = A[2][0] = S20 - S02;
    A[0][3] = A[3][0] = S01 - S10;
    A[1][1] = S00 - S11 - S22;
    A[1][2] = A[2][1] = S01 + S10;
    A[1][3] = A[3][1] = S02 + S20;
    A[2][2] = -S00 + S11 - S22;
    A[2][3] = A[3][2] = S12 + S21;
    A[3][3] = -S00 - S11 + S22;
#pragma unroll
    for (int r = 0; r < 4; ++r)
#pragma unroll
        for (int c = 0; c < 4; ++c)
            V[r][c] = (r == c) ? 1.0f : 0.0f;

#pragma unroll 1
    for (int sweep = 0; sweep < 6; ++sweep) {
        jrot<0, 1>(A, V); jrot<0, 2>(A, V); jrot<0, 3>(A, V);
        jrot<1, 2>(A, V); jrot<1, 3>(A, V); jrot<2, 3>(A, V);
    }

    float best = A[0][0];
    float qw = V[0][0], qx = V[1][0], qy = V[2][0], qz = V[3][0];
#pragma unroll
    for (int i = 1; i < 4; ++i) {
        bool better = A[i][i] > best;
        best = better ? A[i][i] : best;
        qw = better ? V[0][i] : qw;
        qx = better ? V[1][i] : qx;
        qy = better ? V[2][i] : qy;
        qz = better ? V[3][i] : qz;
    }
    float nrm = __builtin_amdgcn_rsqf(qw * qw + qx * qx + qy * qy + qz * qz);
    qw *= nrm; qx *= nrm; qy *= nrm; qz *= nrm;

    float R00 = 1.f - 2.f * (qy * qy + qz * qz);
    float R01 = 2.f * (qx * qy - qw * qz);
    float R02 = 2.f * (qx * qz + qw * qy);
    float R10 = 2.f * (qx * qy + qw * qz);
    float R11 = 1.f - 2.f * (qx * qx + qz * qz);
    float R12 = 2.f * (qy * qz - qw * qx);
    float R20 = 2.f * (qx * qz - qw * qy);
    float R21 = 2.f * (qy * qz + qw * qx);
    float R22 = 1.f - 2.f * (qx * qx + qy * qy);

    Rout[0] = R00; Rout[1] = R01; Rout[2] = R02;
    Rout[3] = R10; Rout[4] = R11; Rout[5] = R12;
    Rout[6] = R20; Rout[7] = R21; Rout[8] = R22;
    tout[0] = cQ0 - (R00 * cP0 + R01 * cP1 + R02 * cP2);
    tout[1] = cQ1 - (R10 * cP0 + R11 * cP1 + R12 * cP2);
    tout[2] = cQ2 - (R20 * cP0 + R21 * cP1 + R22 * cP2);
}

// ---- wave-per-batch fused: grid = ceil(B/WPB) x 128 threads ----
__global__ __launch_bounds__(128, 4) void kabsch_fused(
    const float* __restrict__ points,   // (B, 64, 3)
    const float* __restrict__ weight,   // (B, 64, 24)
    const float* __restrict__ offset,   // (B, 64, 24, 3)
    float* __restrict__ out,            // R (bj,9) then t (bj,3)
    int B, int bj_total)
{
    const int t    = threadIdx.x;
    const int wv   = t >> 6;             // wave in block = batch slot
    const int lane = t & 63;
    const int jj   = lane >> 1;          // joint 0..31 (24..31 masked)
    const int kk   = lane & 1;           // m-half: m in [kk*32, kk*32+32)

    int bw = blockIdx.x * WPB + wv;
    bw = bw < B ? bw : B - 1;            // clamp keeps wave alive for barrier

    __shared__ float sv_s[WPB][NWS][J + 1];   // 1.5 KB prepadded handoff

    if (jj < J) {
        const float* wq = weight + (size_t)bw * (M * J) + (size_t)(kk * 32) * J + jj;
        const float* oq = offset + (size_t)bw * (M * J * 3) + (size_t)(kk * 32) * (J * 3) + jj * 3;
        const float* pq = points + (size_t)bw * (M * 3) + (size_t)(kk * 32) * 3;

        float acc[NACC];
#pragma unroll
        for (int n = 0; n < NACC; ++n) acc[n] = 0.0f;

        // 32 fully-independent iterations: loads pipeline across the unroll,
        // no barriers, no LDS in the accum path.
#pragma unroll
        for (int i = 0; i < M / 2; ++i) {
            float w  = wq[i * J];
            float o0 = oq[i * 72 + 0];
            float o1 = oq[i * 72 + 1];
            float o2 = oq[i * 72 + 2];
            float p0 = pq[i * 3 + 0];
            float p1 = pq[i * 3 + 1];
            float p2 = pq[i * 3 + 2];
            acc[0] += w;
            acc[1] = fmaf(w, o0, acc[1]);  acc[2] = fmaf(w, o1, acc[2]);  acc[3] = fmaf(w, o2, acc[3]);
            acc[4] = fmaf(w, p0, acc[4]);  acc[5] = fmaf(w, p1, acc[5]);  acc[6] = fmaf(w, p2, acc[6]);
            acc[7] += o0; acc[8] += o1; acc[9] += o2;
            acc[10] += p0; acc[11] += p1; acc[12] += p2;
            acc[13] = fmaf(o0, p0, acc[13]); acc[14] = fmaf(o0, p1, acc[14]); acc[15] = fmaf(o0, p2, acc[15]);
            acc[16] = fmaf(o1, p0, acc[16]); acc[17] = fmaf(o1, p1, acc[17]); acc[18] = fmaf(o1, p2, acc[18]);
            acc[19] = fmaf(o2, p0, acc[19]); acc[20] = fmaf(o2, p1, acc[20]); acc[21] = fmaf(o2, p2, acc[21]);
        }

        // pair-reduce over kk (lane^1): 22 cross-lane ops total
#pragma unroll
        for (int n = 0; n < NACC; ++n) acc[n] += __shfl_xor(acc[n], 1);

        if (kk == 0) {
            const float inv = __builtin_amdgcn_rcpf(acc[0]);
            const float cP0 = acc[1] * inv, cP1 = acc[2] * inv, cP2 = acc[3] * inv;
            const float cQ0 = acc[4] * inv, cQ1 = acc[5] * inv, cQ2 = acc[6] * inv;
            const float To0 = acc[7], To1 = acc[8], To2 = acc[9];
            const float Tp0 = acc[10], Tp1 = acc[11], Tp2 = acc[12];
            const float fM = (float)M;
            sv_s[wv][0][jj]  = acc[13] - cP0 * Tp0 - cQ0 * To0 + fM * cP0 * cQ0;
            sv_s[wv][1][jj]  = acc[14] - cP0 * Tp1 - cQ1 * To0 + fM * cP0 * cQ1;
            sv_s[wv][2][jj]  = acc[15] - cP0 * Tp2 - cQ2 * To0 + fM * cP0 * cQ2;
            sv_s[wv][3][jj]  = acc[16] - cP1 * Tp0 - cQ0 * To1 + fM * cP1 * cQ0;
            sv_s[wv][4][jj]  = acc[17] - cP1 * Tp1 - cQ1 * To1 + fM * cP1 * cQ1;
            sv_s[wv][5][jj]  = acc[18] - cP1 * Tp2 - cQ2 * To1 + fM * cP1 * cQ2;
            sv_s[wv][6][jj]  = acc[19] - cP2 * Tp0 - cQ0 * To2 + fM * cP2 * cQ0;
            sv_s[wv][7][jj]  = acc[20] - cP2 * Tp1 - cQ1 * To2 + fM * cP2 * cQ1;
            sv_s[wv][8][jj]  = acc[21] - cP2 * Tp2 - cQ2 * To2 + fM * cP2 * cQ2;
            sv_s[wv][9][jj]  = cP0; sv_s[wv][10][jj] = cP1; sv_s[wv][11][jj] = cP2;
            sv_s[wv][12][jj] = cQ0; sv_s[wv][13][jj] = cQ1; sv_s[wv][14][jj] = cQ2;
        }
    }

    __syncthreads();   // the ONLY barrier

    // solve phase: threads 0..47 (wave 0), one Horn solve each; wave 1 retires
    if (t < WPB * J) {
        const int g  = t / J;
        const int j  = t - g * J;
        int bb = blockIdx.x * WPB + g;
        if (bb < B) {
            float v[NWS];
#pragma unroll
            for (int n = 0; n < NWS; ++n) v[n] = sv_s[g][n][j];
            float Rr[9], tr[3];
            horn_solve(v[0], v[1], v[2], v[3], v[4], v[5], v[6], v[7], v[8],
                       v[9], v[10], v[11], v[12], v[13], v[14], Rr, tr);
            const int bj = bb * J + j;
            float* Rout = out + (size_t)bj * 9;
#pragma unroll
            for (int n = 0; n < 9; ++n) Rout[n] = Rr[n];
            float* tout = out + (size_t)bj_total * 9 + (size_t)bj * 3;
            tout[0] = tr[0]; tout[1] = tr[1]; tout[2] = tr[2];
        }
    }
}

extern "C" void kernel_launch(void* const* d_in, const int* in_sizes, int n_in,
                              void* d_out, int out_size, void* d_ws, size_t ws_size,
                              hipStream_t stream) {
    const float* points = (const float*)d_in[0];
    const float* weight = (const float*)d_in[1];
    const float* offset = (const float*)d_in[2];
    float* out = (float*)d_out;

    int B = in_sizes[0] / (M * 3);
    int bj_total = B * J;
    int grid = (B + WPB - 1) / WPB;

    kabsch_fused<<<grid, 128, 0, stream>>>(points, weight, offset, out, B, bj_total);
}